// Round 1
// baseline (521.069 us; speedup 1.0000x reference)
//
#include <hip/hip_runtime.h>
#include <stdint.h>

#define B_   32
#define DIM_ 16
#define H_   128
#define DM_  256
#define NH_  8
#define WP_  32     // DM/NH
#define C3_  384    // 3*NH*DIM
#define CH_  128    // NH*DIM

// ---------- bf16 <-> f32 bit helpers (no hip_bf16 API; deterministic RNE) ----------
__device__ __forceinline__ unsigned short f2bfu(float v) {
    unsigned int x = __float_as_uint(v);
    x += 0x7fffu + ((x >> 16) & 1u);   // round-to-nearest-even
    return (unsigned short)(x >> 16);
}
__device__ __forceinline__ void unpack8(uint4 u, float* f) {
    f[0] = __uint_as_float(u.x << 16); f[1] = __uint_as_float(u.x & 0xffff0000u);
    f[2] = __uint_as_float(u.y << 16); f[3] = __uint_as_float(u.y & 0xffff0000u);
    f[4] = __uint_as_float(u.z << 16); f[5] = __uint_as_float(u.z & 0xffff0000u);
    f[6] = __uint_as_float(u.w << 16); f[7] = __uint_as_float(u.w & 0xffff0000u);
}

// ============================================================================
// Kernel 1: fused conv1 (grouped 5x1, pad 2 on H) + conv2 (depthwise 1x8, stride 8)
// One thread per (h, wp) position of one (b, g) slice; x patch (5x8) in registers.
// Grid: 32 b * 16 g * 16 htiles = 8192 blocks, 256 threads (8 h x 32 wp).
// ============================================================================
__global__ __launch_bounds__(256) void conv_kernel(
    const float* __restrict__ x, const float* __restrict__ w1,
    const float* __restrict__ w2, unsigned short* __restrict__ y2)
{
    const int bid = blockIdx.x;
    const int ht = bid & 15;
    const int g  = (bid >> 4) & 15;
    const int b  = bid >> 8;
    const int tid = threadIdx.x;
    const int hl = tid >> 5;      // 0..7
    const int wp = tid & 31;      // 0..31
    const int h  = ht * 8 + hl;

    const float* xbase = x + ((size_t)(b * DIM_ + g) * H_) * DM_;

    float xr[5][8];
    #pragma unroll
    for (int t = 0; t < 5; ++t) {
        const int hr = h + t - 2;
        if (hr >= 0 && hr < H_) {
            const float4* p = (const float4*)(xbase + (size_t)hr * DM_ + wp * 8);
            float4 a = p[0], c = p[1];
            xr[t][0] = a.x; xr[t][1] = a.y; xr[t][2] = a.z; xr[t][3] = a.w;
            xr[t][4] = c.x; xr[t][5] = c.y; xr[t][6] = c.z; xr[t][7] = c.w;
        } else {
            #pragma unroll
            for (int j = 0; j < 8; ++j) xr[t][j] = 0.f;
        }
    }

    for (int oc = 0; oc < 24; ++oc) {
        const int o = g * 24 + oc;
        const float* pw1 = w1 + o * 5;
        const float* pw2 = w2 + o * 8;
        float w1r[5], w2r[8];
        #pragma unroll
        for (int t = 0; t < 5; ++t) w1r[t] = pw1[t];
        #pragma unroll
        for (int j = 0; j < 8; ++j) w2r[j] = pw2[j];

        float y = 0.f;
        #pragma unroll
        for (int t = 0; t < 5; ++t) {
            float u = 0.f;
            #pragma unroll
            for (int j = 0; j < 8; ++j) u += w2r[j] * xr[t][j];
            y += w1r[t] * u;
        }
        y2[(((size_t)(b * C3_ + o)) * H_ + h) * WP_ + wp] = f2bfu(y);
    }
}

// ============================================================================
// Kernel 2: attention per (b, ch). q=ch, k=128+ch, v=256+ch conv channels.
// QK: 16x16 thread grid, 8x8 register tile, K=32.
// softmax: rows spread over 16 contiguous lanes, shfl_xor reduce, unnormalized
//          P stored bf16 in LDS (overlaying q/k), denom folded in at the write.
// PV: 16 rowgrp x 4 colgrp x 4 K-split, 8x8 tile, shfl reduce over K-split.
// Writes z[b][d][h][n*32+wp] (d=ch>>3, n=ch&7) bf16 -> proj-friendly layout.
// Grid: 32*128 = 4096 blocks, 256 threads.
// ============================================================================
__global__ __launch_bounds__(256) void attn_kernel(
    const unsigned short* __restrict__ y2, unsigned short* __restrict__ z)
{
    __shared__ float lds[12672];               // 50688 B
    float* qs = lds;                           // [128][32]
    float* kt = lds + 4096;                    // [32][136] (k transposed, padded)
    float* vs = lds + 8448;                    // [128][32]
    float* dn = lds + 12544;                   // [128] softmax denominators
    unsigned short* ps = (unsigned short*)lds; // [128][132] bf16, overlays qs+kt

    const int tid = threadIdx.x;
    const int bid = blockIdx.x;
    const int ch = bid & 127;
    const int b  = bid >> 7;
    const float scale = 0.17677669529663687f;  // 1/sqrt(32)

    const size_t base = ((size_t)(b * C3_) + ch) * (H_ * WP_);
    const uint4* qg = (const uint4*)(y2 + base);
    const uint4* kg = (const uint4*)(y2 + base + (size_t)128 * (H_ * WP_));
    const uint4* vg = (const uint4*)(y2 + base + (size_t)256 * (H_ * WP_));

    // ---- stage q (pre-scaled), k (transposed), v ----
    #pragma unroll
    for (int t = 0; t < 2; ++t) {
        const int ci = tid + t * 256;     // 0..511
        const int hh = ci >> 2;           // row 0..127
        const int w0 = (ci & 3) << 3;     // col {0,8,16,24}
        float f[8];
        unpack8(qg[ci], f);
        #pragma unroll
        for (int j = 0; j < 8; ++j) f[j] *= scale;
        *(float4*)&qs[hh * 32 + w0]     = make_float4(f[0], f[1], f[2], f[3]);
        *(float4*)&qs[hh * 32 + w0 + 4] = make_float4(f[4], f[5], f[6], f[7]);
        unpack8(kg[ci], f);
        #pragma unroll
        for (int j = 0; j < 8; ++j) kt[(w0 + j) * 136 + hh] = f[j];
        unpack8(vg[ci], f);
        *(float4*)&vs[hh * 32 + w0]     = make_float4(f[0], f[1], f[2], f[3]);
        *(float4*)&vs[hh * 32 + w0 + 4] = make_float4(f[4], f[5], f[6], f[7]);
    }
    __syncthreads();

    // ---- QK^T: thread (ty,tx) computes rows 8ty..+7 x cols 8tx..+7 ----
    const int ty = tid >> 4, tx = tid & 15;
    float s[8][8];
    #pragma unroll
    for (int r = 0; r < 8; ++r)
        #pragma unroll
        for (int c = 0; c < 8; ++c) s[r][c] = 0.f;

    #pragma unroll
    for (int d4 = 0; d4 < 8; ++d4) {
        const int d = d4 << 2;
        float4 qf[8];
        #pragma unroll
        for (int r = 0; r < 8; ++r) qf[r] = *(const float4*)&qs[(ty * 8 + r) * 32 + d];
        float kc[4][8];
        #pragma unroll
        for (int i = 0; i < 4; ++i) {
            float4 a  = *(const float4*)&kt[(d + i) * 136 + tx * 8];
            float4 bb = *(const float4*)&kt[(d + i) * 136 + tx * 8 + 4];
            kc[i][0] = a.x;  kc[i][1] = a.y;  kc[i][2] = a.z;  kc[i][3] = a.w;
            kc[i][4] = bb.x; kc[i][5] = bb.y; kc[i][6] = bb.z; kc[i][7] = bb.w;
        }
        #pragma unroll
        for (int r = 0; r < 8; ++r)
            #pragma unroll
            for (int c = 0; c < 8; ++c)
                s[r][c] += qf[r].x * kc[0][c] + qf[r].y * kc[1][c]
                         + qf[r].z * kc[2][c] + qf[r].w * kc[3][c];
    }

    // ---- softmax (rows across 16 lanes; unnormalized P, denom deferred) ----
    float dnr[8];
    #pragma unroll
    for (int r = 0; r < 8; ++r) {
        float m = s[r][0];
        #pragma unroll
        for (int c = 1; c < 8; ++c) m = fmaxf(m, s[r][c]);
        #pragma unroll
        for (int off = 1; off < 16; off <<= 1) m = fmaxf(m, __shfl_xor(m, off));
        float sum = 0.f;
        #pragma unroll
        for (int c = 0; c < 8; ++c) { float p = __expf(s[r][c] - m); s[r][c] = p; sum += p; }
        #pragma unroll
        for (int off = 1; off < 16; off <<= 1) sum += __shfl_xor(sum, off);
        dnr[r] = sum;
    }

    __syncthreads();   // q/k reads done; safe to overlay ps

    #pragma unroll
    for (int r = 0; r < 8; ++r) {
        const int row = ty * 8 + r;
        unsigned int pk[4];
        #pragma unroll
        for (int q2 = 0; q2 < 4; ++q2)
            pk[q2] = (unsigned int)f2bfu(s[r][2 * q2]) |
                     ((unsigned int)f2bfu(s[r][2 * q2 + 1]) << 16);
        *(uint2*)&ps[row * 132 + tx * 8]     = make_uint2(pk[0], pk[1]);
        *(uint2*)&ps[row * 132 + tx * 8 + 4] = make_uint2(pk[2], pk[3]);
    }
    if (tx == 0) {
        #pragma unroll
        for (int r = 0; r < 8; ++r) dn[ty * 8 + r] = dnr[r];
    }
    __syncthreads();

    // ---- PV: thread (rg, cg, kq): rows 8rg..+7, cols 8cg..+7, j in [32kq,32kq+32) ----
    const int rg = tid >> 4;
    const int cg = (tid >> 2) & 3;
    const int kq = tid & 3;
    float acc[8][8];
    #pragma unroll
    for (int r = 0; r < 8; ++r)
        #pragma unroll
        for (int c = 0; c < 8; ++c) acc[r][c] = 0.f;

    #pragma unroll
    for (int j4 = 0; j4 < 8; ++j4) {
        const int j = kq * 32 + j4 * 4;
        float pf[8][4];
        #pragma unroll
        for (int r = 0; r < 8; ++r) {
            uint2 u = *(const uint2*)&ps[(rg * 8 + r) * 132 + j];
            pf[r][0] = __uint_as_float(u.x << 16);
            pf[r][1] = __uint_as_float(u.x & 0xffff0000u);
            pf[r][2] = __uint_as_float(u.y << 16);
            pf[r][3] = __uint_as_float(u.y & 0xffff0000u);
        }
        float vf[4][8];
        #pragma unroll
        for (int i = 0; i < 4; ++i) {
            float4 a  = *(const float4*)&vs[(j + i) * 32 + cg * 8];
            float4 bb = *(const float4*)&vs[(j + i) * 32 + cg * 8 + 4];
            vf[i][0] = a.x;  vf[i][1] = a.y;  vf[i][2] = a.z;  vf[i][3] = a.w;
            vf[i][4] = bb.x; vf[i][5] = bb.y; vf[i][6] = bb.z; vf[i][7] = bb.w;
        }
        #pragma unroll
        for (int r = 0; r < 8; ++r)
            #pragma unroll
            for (int c = 0; c < 8; ++c)
                acc[r][c] += pf[r][0] * vf[0][c] + pf[r][1] * vf[1][c]
                           + pf[r][2] * vf[2][c] + pf[r][3] * vf[3][c];
    }

    // reduce over kq (lanes tid&3) via butterfly
    #pragma unroll
    for (int r = 0; r < 8; ++r)
        #pragma unroll
        for (int c = 0; c < 8; ++c) {
            acc[r][c] += __shfl_xor(acc[r][c], 1);
            acc[r][c] += __shfl_xor(acc[r][c], 2);
        }

    if (kq == 0) {
        const int dd = ch >> 3, nn = ch & 7;
        unsigned short* zb = z + ((size_t)(b * DIM_ + dd)) * (H_ * DM_);
        #pragma unroll
        for (int r = 0; r < 8; ++r) {
            const int row = rg * 8 + r;
            const float inv = 1.f / dn[row];
            unsigned int pk[4];
            #pragma unroll
            for (int q2 = 0; q2 < 4; ++q2) {
                float v0 = acc[r][2 * q2] * inv, v1 = acc[r][2 * q2 + 1] * inv;
                pk[q2] = (unsigned int)f2bfu(v0) | ((unsigned int)f2bfu(v1) << 16);
            }
            *(uint4*)&zb[(size_t)row * DM_ + nn * 32 + cg * 8] =
                make_uint4(pk[0], pk[1], pk[2], pk[3]);
        }
    }
}

// ============================================================================
// Kernel 3: out projection per (b, d): out[128][256] = z[128][256] @ W^T + bias
// A staged bf16 in LDS; W staged transposed fp32 in 16-col chunks.
// Thread tile 8h x 16m (grid 16x16). Grid: 512 blocks, 256 threads.
// ============================================================================
__global__ __launch_bounds__(256) void proj_kernel(
    const unsigned short* __restrict__ z, const float* __restrict__ w,
    const float* __restrict__ bias, float* __restrict__ out)
{
    __shared__ unsigned short As[128 * 256];   // 64 KB
    __shared__ float Wt[16 * 256];             // 16 KB

    const int tid = threadIdx.x;
    const int bid = blockIdx.x;                // b*16 + d
    const unsigned short* zs = z + (size_t)bid * (128 * 256);

    #pragma unroll
    for (int t = 0; t < 16; ++t)
        ((uint4*)As)[tid + t * 256] = ((const uint4*)zs)[tid + t * 256];

    const int hg = tid >> 4, mg = tid & 15;
    float acc[8][16];
    #pragma unroll
    for (int r = 0; r < 8; ++r)
        #pragma unroll
        for (int c = 0; c < 16; ++c) acc[r][c] = 0.f;

    const float* wrow = w + (size_t)tid * 256;

    for (int eb = 0; eb < 16; ++eb) {
        float wv[16];
        #pragma unroll
        for (int i4 = 0; i4 < 4; ++i4) {
            float4 a = ((const float4*)(wrow + eb * 16))[i4];
            wv[i4 * 4 + 0] = a.x; wv[i4 * 4 + 1] = a.y;
            wv[i4 * 4 + 2] = a.z; wv[i4 * 4 + 3] = a.w;
        }
        __syncthreads();   // protect Wt from previous iteration's readers
        #pragma unroll
        for (int i = 0; i < 16; ++i) Wt[i * 256 + tid] = wv[i];
        __syncthreads();   // Wt (and on eb==0, As) visible

        #pragma unroll
        for (int i4 = 0; i4 < 4; ++i4) {
            float af[8][4];
            #pragma unroll
            for (int r = 0; r < 8; ++r) {
                uint2 u = *(const uint2*)&As[(hg * 8 + r) * 256 + eb * 16 + i4 * 4];
                af[r][0] = __uint_as_float(u.x << 16);
                af[r][1] = __uint_as_float(u.x & 0xffff0000u);
                af[r][2] = __uint_as_float(u.y << 16);
                af[r][3] = __uint_as_float(u.y & 0xffff0000u);
            }
            #pragma unroll
            for (int ii = 0; ii < 4; ++ii) {
                const float* wr = &Wt[(i4 * 4 + ii) * 256 + mg * 16];
                float4 w0 = *(const float4*)(wr);
                float4 w1 = *(const float4*)(wr + 4);
                float4 w2 = *(const float4*)(wr + 8);
                float4 w3 = *(const float4*)(wr + 12);
                float wf[16] = { w0.x, w0.y, w0.z, w0.w, w1.x, w1.y, w1.z, w1.w,
                                 w2.x, w2.y, w2.z, w2.w, w3.x, w3.y, w3.z, w3.w };
                #pragma unroll
                for (int r = 0; r < 8; ++r) {
                    const float a = af[r][ii];
                    #pragma unroll
                    for (int c = 0; c < 16; ++c) acc[r][c] += a * wf[c];
                }
            }
        }
    }

    float bs[16];
    {
        const float4* bp = (const float4*)(bias + mg * 16);
        float4 b0 = bp[0], b1 = bp[1], b2 = bp[2], b3 = bp[3];
        bs[0] = b0.x; bs[1] = b0.y; bs[2]  = b0.z; bs[3]  = b0.w;
        bs[4] = b1.x; bs[5] = b1.y; bs[6]  = b1.z; bs[7]  = b1.w;
        bs[8] = b2.x; bs[9] = b2.y; bs[10] = b2.z; bs[11] = b2.w;
        bs[12] = b3.x; bs[13] = b3.y; bs[14] = b3.z; bs[15] = b3.w;
    }
    float* ob = out + (size_t)bid * (128 * 256);
    #pragma unroll
    for (int r = 0; r < 8; ++r) {
        const int row = hg * 8 + r;
        #pragma unroll
        for (int c4 = 0; c4 < 4; ++c4) {
            float4 vv = make_float4(acc[r][c4 * 4 + 0] + bs[c4 * 4 + 0],
                                    acc[r][c4 * 4 + 1] + bs[c4 * 4 + 1],
                                    acc[r][c4 * 4 + 2] + bs[c4 * 4 + 2],
                                    acc[r][c4 * 4 + 3] + bs[c4 * 4 + 3]);
            *(float4*)&ob[(size_t)row * 256 + mg * 16 + c4 * 4] = vv;
        }
    }
}

// ============================================================================
extern "C" void kernel_launch(void* const* d_in, const int* in_sizes, int n_in,
                              void* d_out, int out_size, void* d_ws, size_t ws_size,
                              hipStream_t stream)
{
    const float* x  = (const float*)d_in[0];
    const float* w1 = (const float*)d_in[1];
    const float* w2 = (const float*)d_in[2];
    const float* wo = (const float*)d_in[3];
    const float* wb = (const float*)d_in[4];
    float* out = (float*)d_out;

    unsigned short* y2 = (unsigned short*)d_ws;                    // 100,663,296 B
    unsigned short* zz = y2 + (size_t)B_ * C3_ * H_ * WP_;         // + 33,554,432 B

    conv_kernel<<<dim3(8192), dim3(256), 0, stream>>>(x, w1, w2, y2);
    attn_kernel<<<dim3(4096), dim3(256), 0, stream>>>(y2, zz);
    proj_kernel<<<dim3(512),  dim3(256), 0, stream>>>(zz, wo, wb, out);
}

// Round 2
// 220.985 us; speedup vs baseline: 2.3579x; 2.3579x over previous
//
#include <hip/hip_runtime.h>
#include <stdint.h>

#define B_   32
#define DIM_ 16
#define H_   128
#define DM_  256
#define NH_  8
#define WP_  32     // DM/NH
#define C3_  384    // 3*NH*DIM

typedef short bf16x8 __attribute__((ext_vector_type(8)));
typedef float f32x4  __attribute__((ext_vector_type(4)));

__device__ __forceinline__ unsigned short f2bfu(float v) {
    unsigned int x = __float_as_uint(v);
    x += 0x7fffu + ((x >> 16) & 1u);   // RNE
    return (unsigned short)(x >> 16);
}
__device__ __forceinline__ unsigned cvtpk(float lo, float hi) {
    unsigned r;
    asm("v_cvt_pk_bf16_f32 %0, %1, %2" : "=v"(r) : "v"(lo), "v"(hi));
    return r;
}

// ============================================================================
// Kernel 1: fused conv1 (grouped 5x1, pad 2 on H) + conv2 (depthwise 1x8 s8).
// Unchanged from round 1 (passed; ~compute-bound fp32, revisit if dominant).
// ============================================================================
__global__ __launch_bounds__(256) void conv_kernel(
    const float* __restrict__ x, const float* __restrict__ w1,
    const float* __restrict__ w2, unsigned short* __restrict__ y2)
{
    const int bid = blockIdx.x;
    const int ht = bid & 15;
    const int g  = (bid >> 4) & 15;
    const int b  = bid >> 8;
    const int tid = threadIdx.x;
    const int hl = tid >> 5;
    const int wp = tid & 31;
    const int h  = ht * 8 + hl;

    const float* xbase = x + ((size_t)(b * DIM_ + g) * H_) * DM_;

    float xr[5][8];
    #pragma unroll
    for (int t = 0; t < 5; ++t) {
        const int hr = h + t - 2;
        if (hr >= 0 && hr < H_) {
            const float4* p = (const float4*)(xbase + (size_t)hr * DM_ + wp * 8);
            float4 a = p[0], c = p[1];
            xr[t][0] = a.x; xr[t][1] = a.y; xr[t][2] = a.z; xr[t][3] = a.w;
            xr[t][4] = c.x; xr[t][5] = c.y; xr[t][6] = c.z; xr[t][7] = c.w;
        } else {
            #pragma unroll
            for (int j = 0; j < 8; ++j) xr[t][j] = 0.f;
        }
    }

    for (int oc = 0; oc < 24; ++oc) {
        const int o = g * 24 + oc;
        const float* pw1 = w1 + o * 5;
        const float* pw2 = w2 + o * 8;
        float w1r[5], w2r[8];
        #pragma unroll
        for (int t = 0; t < 5; ++t) w1r[t] = pw1[t];
        #pragma unroll
        for (int j = 0; j < 8; ++j) w2r[j] = pw2[j];

        float y = 0.f;
        #pragma unroll
        for (int t = 0; t < 5; ++t) {
            float u = 0.f;
            #pragma unroll
            for (int j = 0; j < 8; ++j) u += w2r[j] * xr[t][j];
            y += w1r[t] * u;
        }
        y2[(((size_t)(b * C3_ + o)) * H_ + h) * WP_ + wp] = f2bfu(y);
    }
}

// ============================================================================
// Kernel 2: MFMA attention per (b, ch).
// S^T = K·Q^T via mfma_f32_16x16x32_bf16 (both operands A-fragment pattern).
// Softmax k-reduction is per-lane over 32 values + shfl_xor(16,32).
// P normalized -> bf16 -> XOR-swizzled LDS. O^T = Vt·P^T (both A-pattern).
// LDS 40KB: P[128][128]bf16 @0 (overlays Qs@0/Ks@8192 staging), Vt @32768.
// ============================================================================
__global__ __launch_bounds__(256) void attn_kernel(
    const unsigned short* __restrict__ y2, unsigned short* __restrict__ z)
{
    __shared__ __align__(16) unsigned char sm[40960];

    const int tid = threadIdx.x;
    const int ch = blockIdx.x & 127, b = blockIdx.x >> 7;
    const size_t base = ((size_t)(b * C3_ + ch)) * 4096;
    const uint4* qg = (const uint4*)(y2 + base);
    const uint4* kg = (const uint4*)(y2 + base + 128 * 4096);
    const uint4* vg = (const uint4*)(y2 + base + 256 * 4096);

    // ---- stage: Q @0, K @8192 ([128][32] bf16, 16B-chunk ^ ((row>>1)&3));
    //      V transposed directly to Vt @32768 ([32 d][128 k], chunk ^ (d&7)).
    #pragma unroll
    for (int r = 0; r < 2; ++r) {
        const int ci  = tid + r * 256;      // 0..511 uint4s
        const int row = ci >> 2;            // 0..127
        const int c   = ci & 3;             // 16B chunk in row
        const int cx  = c ^ ((row >> 1) & 3);
        *(uint4*)(sm + row * 64 + cx * 16)        = qg[ci];
        *(uint4*)(sm + 8192 + row * 64 + cx * 16) = kg[ci];
        uint4 v = vg[ci];
        unsigned short vs[8];
        vs[0] = (unsigned short)(v.x & 0xffffu); vs[1] = (unsigned short)(v.x >> 16);
        vs[2] = (unsigned short)(v.y & 0xffffu); vs[3] = (unsigned short)(v.y >> 16);
        vs[4] = (unsigned short)(v.z & 0xffffu); vs[5] = (unsigned short)(v.z >> 16);
        vs[6] = (unsigned short)(v.w & 0xffffu); vs[7] = (unsigned short)(v.w >> 16);
        const int d0 = c * 8;
        #pragma unroll
        for (int j = 0; j < 8; ++j) {
            const int d = d0 + j;
            *(unsigned short*)(sm + 32768 + d * 256 + ((row * 2) ^ ((d & 7) << 4))) = vs[j];
        }
    }
    __syncthreads();

    const int l  = tid & 63, wv = tid >> 6;
    const int lm = l & 15,  lk = l >> 4;

    // ---- QK^T: S^T[k][q], wave wv owns q columns 32wv..32wv+31 ----
    bf16x8 qf[2];
    #pragma unroll
    for (int t = 0; t < 2; ++t) {
        const int q = (wv * 2 + t) * 16 + lm;
        qf[t] = *(const bf16x8*)(sm + q * 64 + ((lk ^ ((q >> 1) & 3)) << 4));
    }
    f32x4 acc[8][2];
    #pragma unroll
    for (int rt = 0; rt < 8; ++rt) {
        acc[rt][0] = 0; acc[rt][1] = 0;
    }
    #pragma unroll
    for (int rt = 0; rt < 8; ++rt) {
        const int kr = rt * 16 + lm;
        bf16x8 kf = *(const bf16x8*)(sm + 8192 + kr * 64 + ((lk ^ ((kr >> 1) & 3)) << 4));
        acc[rt][0] = __builtin_amdgcn_mfma_f32_16x16x32_bf16(kf, qf[0], acc[rt][0], 0, 0, 0);
        acc[rt][1] = __builtin_amdgcn_mfma_f32_16x16x32_bf16(kf, qf[1], acc[rt][1], 0, 0, 0);
    }

    // ---- softmax: lane holds k = rt*16 + lk*4 + reg for q = ct*16 + lm ----
    const float Cc = 0.17677669529663687f * 1.4426950408889634f; // scale*log2e
    float inv[2];
    #pragma unroll
    for (int t = 0; t < 2; ++t) {
        float m = acc[0][t][0];
        #pragma unroll
        for (int rt = 0; rt < 8; ++rt)
            #pragma unroll
            for (int rg = 0; rg < 4; ++rg) m = fmaxf(m, acc[rt][t][rg]);
        m = fmaxf(m, __shfl_xor(m, 16));
        m = fmaxf(m, __shfl_xor(m, 32));
        float s = 0.f;
        #pragma unroll
        for (int rt = 0; rt < 8; ++rt)
            #pragma unroll
            for (int rg = 0; rg < 4; ++rg) {
                float p = exp2f((acc[rt][t][rg] - m) * Cc);
                acc[rt][t][rg] = p; s += p;
            }
        s += __shfl_xor(s, 16);
        s += __shfl_xor(s, 32);
        inv[t] = 1.0f / s;
    }

    __syncthreads();   // all Q/K reads done -> safe to overlay P

    // ---- write normalized P (bf16) to swizzled LDS ----
    #pragma unroll
    for (int t = 0; t < 2; ++t) {
        const int q = (wv * 2 + t) * 16 + lm;
        #pragma unroll
        for (int rt = 0; rt < 8; ++rt) {
            unsigned u0 = cvtpk(acc[rt][t][0] * inv[t], acc[rt][t][1] * inv[t]);
            unsigned u1 = cvtpk(acc[rt][t][2] * inv[t], acc[rt][t][3] * inv[t]);
            const int kb = rt * 32 + lk * 8;   // byte offset = k0*2
            *(uint2*)(sm + q * 256 + (kb ^ ((q & 7) << 4))) = make_uint2(u0, u1);
        }
    }
    __syncthreads();

    // ---- PV: O^T[d][q] = Vt·P^T ----
    f32x4 o[2][2];
    o[0][0] = 0; o[0][1] = 0; o[1][0] = 0; o[1][1] = 0;
    #pragma unroll
    for (int kc = 0; kc < 4; ++kc) {
        const int cb = kc * 64 + lk * 16;
        bf16x8 av[2], bp[2];
        #pragma unroll
        for (int dt = 0; dt < 2; ++dt) {
            const int d = dt * 16 + lm;
            av[dt] = *(const bf16x8*)(sm + 32768 + d * 256 + (cb ^ ((d & 7) << 4)));
        }
        #pragma unroll
        for (int t = 0; t < 2; ++t) {
            const int q = (wv * 2 + t) * 16 + lm;
            bp[t] = *(const bf16x8*)(sm + q * 256 + (cb ^ ((q & 7) << 4)));
        }
        #pragma unroll
        for (int dt = 0; dt < 2; ++dt)
            #pragma unroll
            for (int t = 0; t < 2; ++t)
                o[dt][t] = __builtin_amdgcn_mfma_f32_16x16x32_bf16(av[dt], bp[t], o[dt][t], 0, 0, 0);
    }

    // ---- epilogue: lane holds d = dt*16 + lk*4 + reg, q = (2wv+t)*16 + lm ----
    const int dd = ch >> 3, nn = ch & 7;
    unsigned short* zb = z + ((size_t)(b * DIM_ + dd)) * (H_ * DM_);
    #pragma unroll
    for (int dt = 0; dt < 2; ++dt)
        #pragma unroll
        for (int t = 0; t < 2; ++t) {
            const int q  = (wv * 2 + t) * 16 + lm;
            const int d0 = dt * 16 + lk * 4;
            unsigned u0 = cvtpk(o[dt][t][0], o[dt][t][1]);
            unsigned u1 = cvtpk(o[dt][t][2], o[dt][t][3]);
            *(uint2*)(zb + (size_t)q * DM_ + nn * 32 + d0) = make_uint2(u0, u1);
        }
}

// ============================================================================
// Kernel 3: W -> bf16 hi/lo split (runs after attn; writes into dead y2 region)
// ============================================================================
__global__ __launch_bounds__(256) void prep_w(
    const float* __restrict__ w, unsigned short* __restrict__ wh,
    unsigned short* __restrict__ wl)
{
    const int i = blockIdx.x * 1024 + threadIdx.x * 4;
    float4 v = *(const float4*)(w + i);
    float vv[4] = { v.x, v.y, v.z, v.w };
    unsigned short h[4], lo[4];
    #pragma unroll
    for (int j = 0; j < 4; ++j) {
        h[j] = f2bfu(vv[j]);
        float hf = __uint_as_float(((unsigned)h[j]) << 16);
        lo[j] = f2bfu(vv[j] - hf);
    }
    *(uint2*)(wh + i) = make_uint2((unsigned)h[0] | ((unsigned)h[1] << 16),
                                   (unsigned)h[2] | ((unsigned)h[3] << 16));
    *(uint2*)(wl + i) = make_uint2((unsigned)lo[0] | ((unsigned)lo[1] << 16),
                                   (unsigned)lo[2] | ((unsigned)lo[3] << 16));
}

// ============================================================================
// Kernel 4: MFMA out-projection per (b,d): out = z·(Wh+Wl)^T + bias.
// z staged in swizzled LDS (64KB); W fragments straight from L2 (256KB total).
// ============================================================================
__global__ __launch_bounds__(256) void proj_kernel(
    const unsigned short* __restrict__ zz, const unsigned short* __restrict__ wh,
    const unsigned short* __restrict__ wl, const float* __restrict__ bias,
    float* __restrict__ out)
{
    __shared__ __align__(16) unsigned char sm[65536];
    const int tid = threadIdx.x;
    const unsigned short* zs = zz + (size_t)blockIdx.x * 32768;

    #pragma unroll
    for (int r = 0; r < 16; ++r) {
        const int ci  = tid + r * 256;   // uint4 index 0..4095
        const int row = ci >> 5;         // 0..127
        const int c   = ci & 31;         // 16B chunk
        *(uint4*)(sm + row * 512 + ((c << 4) ^ ((row & 7) << 4))) = ((const uint4*)zs)[ci];
    }
    __syncthreads();

    const int l = tid & 63, wv = tid >> 6, lm = l & 15, lk = l >> 4;

    f32x4 acc[2][16];
    #pragma unroll
    for (int t = 0; t < 2; ++t)
        #pragma unroll
        for (int nt = 0; nt < 16; ++nt) acc[t][nt] = 0;

    const unsigned short* wptr[2] = { wh, wl };
    #pragma unroll
    for (int ph = 0; ph < 2; ++ph) {
        const unsigned short* w = wptr[ph];
        for (int kc = 0; kc < 8; ++kc) {
            bf16x8 a[2];
            #pragma unroll
            for (int t = 0; t < 2; ++t) {
                const int row = (wv * 2 + t) * 16 + lm;
                a[t] = *(const bf16x8*)(sm + row * 512 + ((kc * 64 + lk * 16) ^ ((row & 7) << 4)));
            }
            #pragma unroll
            for (int nt = 0; nt < 16; ++nt) {
                bf16x8 bf = *(const bf16x8*)(w + (size_t)(nt * 16 + lm) * 256 + kc * 32 + lk * 8);
                acc[0][nt] = __builtin_amdgcn_mfma_f32_16x16x32_bf16(a[0], bf, acc[0][nt], 0, 0, 0);
                acc[1][nt] = __builtin_amdgcn_mfma_f32_16x16x32_bf16(a[1], bf, acc[1][nt], 0, 0, 0);
            }
        }
    }

    float* ob = out + (size_t)blockIdx.x * 32768;
    #pragma unroll
    for (int nt = 0; nt < 16; ++nt) {
        const float bv = bias[nt * 16 + lm];
        #pragma unroll
        for (int t = 0; t < 2; ++t) {
            const int rbase = (wv * 2 + t) * 16 + lk * 4;
            #pragma unroll
            for (int rg = 0; rg < 4; ++rg)
                ob[(size_t)(rbase + rg) * 256 + nt * 16 + lm] = acc[t][nt][rg] + bv;
        }
    }
}

// ============================================================================
extern "C" void kernel_launch(void* const* d_in, const int* in_sizes, int n_in,
                              void* d_out, int out_size, void* d_ws, size_t ws_size,
                              hipStream_t stream)
{
    const float* x  = (const float*)d_in[0];
    const float* w1 = (const float*)d_in[1];
    const float* w2 = (const float*)d_in[2];
    const float* wo = (const float*)d_in[3];
    const float* wb = (const float*)d_in[4];
    float* out = (float*)d_out;

    unsigned short* y2 = (unsigned short*)d_ws;                    // 100,663,296 B
    unsigned short* zz = y2 + (size_t)B_ * C3_ * H_ * WP_;         // + 33,554,432 B
    unsigned short* wh = y2;                                       // overlays dead y2 (after attn)
    unsigned short* wl = y2 + 65536;

    conv_kernel<<<dim3(8192), dim3(256), 0, stream>>>(x, w1, w2, y2);
    attn_kernel<<<dim3(4096), dim3(256), 0, stream>>>(y2, zz);
    prep_w<<<dim3(64), dim3(256), 0, stream>>>(wo, wh, wl);
    proj_kernel<<<dim3(512), dim3(256), 0, stream>>>(zz, wh, wl, wb, out);
}

// Round 3
// 146.384 us; speedup vs baseline: 3.5596x; 1.5096x over previous
//
#include <hip/hip_runtime.h>
#include <stdint.h>

#define B_   32
#define DIM_ 16
#define H_   128
#define DM_  256
#define NH_  8
#define WP_  32     // DM/NH
#define C3_  384    // 3*NH*DIM

typedef short bf16x8 __attribute__((ext_vector_type(8)));
typedef float f32x4  __attribute__((ext_vector_type(4)));

__device__ __forceinline__ unsigned short f2bfu(float v) {
    unsigned int x = __float_as_uint(v);
    x += 0x7fffu + ((x >> 16) & 1u);   // RNE
    return (unsigned short)(x >> 16);
}
__device__ __forceinline__ unsigned cvtpk(float lo, float hi) {
    unsigned r;
    asm("v_cvt_pk_bf16_f32 %0, %1, %2" : "=v"(r) : "v"(lo), "v"(hi));
    return r;
}
// async global->LDS, 16B per lane; lds dest = wave-uniform base + lane*16
__device__ __forceinline__ void gl_lds16(const void* g, void* l) {
    __builtin_amdgcn_global_load_lds(
        (const __attribute__((address_space(1))) unsigned int*)g,
        (__attribute__((address_space(3))) unsigned int*)l, 16, 0, 0);
}

// ============================================================================
// Kernel 1: fused conv1 (grouped 5x1, pad 2 on H) + conv2 (depthwise 1x8 s8).
// Unchanged (known-good).
// ============================================================================
__global__ __launch_bounds__(256) void conv_kernel(
    const float* __restrict__ x, const float* __restrict__ w1,
    const float* __restrict__ w2, unsigned short* __restrict__ y2)
{
    const int bid = blockIdx.x;
    const int ht = bid & 15;
    const int g  = (bid >> 4) & 15;
    const int b  = bid >> 8;
    const int tid = threadIdx.x;
    const int hl = tid >> 5;
    const int wp = tid & 31;
    const int h  = ht * 8 + hl;

    const float* xbase = x + ((size_t)(b * DIM_ + g) * H_) * DM_;

    float xr[5][8];
    #pragma unroll
    for (int t = 0; t < 5; ++t) {
        const int hr = h + t - 2;
        if (hr >= 0 && hr < H_) {
            const float4* p = (const float4*)(xbase + (size_t)hr * DM_ + wp * 8);
            float4 a = p[0], c = p[1];
            xr[t][0] = a.x; xr[t][1] = a.y; xr[t][2] = a.z; xr[t][3] = a.w;
            xr[t][4] = c.x; xr[t][5] = c.y; xr[t][6] = c.z; xr[t][7] = c.w;
        } else {
            #pragma unroll
            for (int j = 0; j < 8; ++j) xr[t][j] = 0.f;
        }
    }

    for (int oc = 0; oc < 24; ++oc) {
        const int o = g * 24 + oc;
        const float* pw1 = w1 + o * 5;
        const float* pw2 = w2 + o * 8;
        float w1r[5], w2r[8];
        #pragma unroll
        for (int t = 0; t < 5; ++t) w1r[t] = pw1[t];
        #pragma unroll
        for (int j = 0; j < 8; ++j) w2r[j] = pw2[j];

        float y = 0.f;
        #pragma unroll
        for (int t = 0; t < 5; ++t) {
            float u = 0.f;
            #pragma unroll
            for (int j = 0; j < 8; ++j) u += w2r[j] * xr[t][j];
            y += w1r[t] * u;
        }
        y2[(((size_t)(b * C3_ + o)) * H_ + h) * WP_ + wp] = f2bfu(y);
    }
}

// ============================================================================
// Kernel 2: MFMA attention per (b, ch). Unchanged (known-good).
// ============================================================================
__global__ __launch_bounds__(256) void attn_kernel(
    const unsigned short* __restrict__ y2, unsigned short* __restrict__ z)
{
    __shared__ __align__(16) unsigned char sm[40960];

    const int tid = threadIdx.x;
    const int ch = blockIdx.x & 127, b = blockIdx.x >> 7;
    const size_t base = ((size_t)(b * C3_ + ch)) * 4096;
    const uint4* qg = (const uint4*)(y2 + base);
    const uint4* kg = (const uint4*)(y2 + base + 128 * 4096);
    const uint4* vg = (const uint4*)(y2 + base + 256 * 4096);

    #pragma unroll
    for (int r = 0; r < 2; ++r) {
        const int ci  = tid + r * 256;
        const int row = ci >> 2;
        const int c   = ci & 3;
        const int cx  = c ^ ((row >> 1) & 3);
        *(uint4*)(sm + row * 64 + cx * 16)        = qg[ci];
        *(uint4*)(sm + 8192 + row * 64 + cx * 16) = kg[ci];
        uint4 v = vg[ci];
        unsigned short vs[8];
        vs[0] = (unsigned short)(v.x & 0xffffu); vs[1] = (unsigned short)(v.x >> 16);
        vs[2] = (unsigned short)(v.y & 0xffffu); vs[3] = (unsigned short)(v.y >> 16);
        vs[4] = (unsigned short)(v.z & 0xffffu); vs[5] = (unsigned short)(v.z >> 16);
        vs[6] = (unsigned short)(v.w & 0xffffu); vs[7] = (unsigned short)(v.w >> 16);
        const int d0 = c * 8;
        #pragma unroll
        for (int j = 0; j < 8; ++j) {
            const int d = d0 + j;
            *(unsigned short*)(sm + 32768 + d * 256 + ((row * 2) ^ ((d & 7) << 4))) = vs[j];
        }
    }
    __syncthreads();

    const int l  = tid & 63, wv = tid >> 6;
    const int lm = l & 15,  lk = l >> 4;

    bf16x8 qf[2];
    #pragma unroll
    for (int t = 0; t < 2; ++t) {
        const int q = (wv * 2 + t) * 16 + lm;
        qf[t] = *(const bf16x8*)(sm + q * 64 + ((lk ^ ((q >> 1) & 3)) << 4));
    }
    f32x4 acc[8][2];
    #pragma unroll
    for (int rt = 0; rt < 8; ++rt) {
        acc[rt][0] = 0; acc[rt][1] = 0;
    }
    #pragma unroll
    for (int rt = 0; rt < 8; ++rt) {
        const int kr = rt * 16 + lm;
        bf16x8 kf = *(const bf16x8*)(sm + 8192 + kr * 64 + ((lk ^ ((kr >> 1) & 3)) << 4));
        acc[rt][0] = __builtin_amdgcn_mfma_f32_16x16x32_bf16(kf, qf[0], acc[rt][0], 0, 0, 0);
        acc[rt][1] = __builtin_amdgcn_mfma_f32_16x16x32_bf16(kf, qf[1], acc[rt][1], 0, 0, 0);
    }

    const float Cc = 0.17677669529663687f * 1.4426950408889634f;
    float inv[2];
    #pragma unroll
    for (int t = 0; t < 2; ++t) {
        float m = acc[0][t][0];
        #pragma unroll
        for (int rt = 0; rt < 8; ++rt)
            #pragma unroll
            for (int rg = 0; rg < 4; ++rg) m = fmaxf(m, acc[rt][t][rg]);
        m = fmaxf(m, __shfl_xor(m, 16));
        m = fmaxf(m, __shfl_xor(m, 32));
        float s = 0.f;
        #pragma unroll
        for (int rt = 0; rt < 8; ++rt)
            #pragma unroll
            for (int rg = 0; rg < 4; ++rg) {
                float p = exp2f((acc[rt][t][rg] - m) * Cc);
                acc[rt][t][rg] = p; s += p;
            }
        s += __shfl_xor(s, 16);
        s += __shfl_xor(s, 32);
        inv[t] = 1.0f / s;
    }

    __syncthreads();

    #pragma unroll
    for (int t = 0; t < 2; ++t) {
        const int q = (wv * 2 + t) * 16 + lm;
        #pragma unroll
        for (int rt = 0; rt < 8; ++rt) {
            unsigned u0 = cvtpk(acc[rt][t][0] * inv[t], acc[rt][t][1] * inv[t]);
            unsigned u1 = cvtpk(acc[rt][t][2] * inv[t], acc[rt][t][3] * inv[t]);
            const int kb = rt * 32 + lk * 8;
            *(uint2*)(sm + q * 256 + (kb ^ ((q & 7) << 4))) = make_uint2(u0, u1);
        }
    }
    __syncthreads();

    f32x4 o[2][2];
    o[0][0] = 0; o[0][1] = 0; o[1][0] = 0; o[1][1] = 0;
    #pragma unroll
    for (int kc = 0; kc < 4; ++kc) {
        const int cb = kc * 64 + lk * 16;
        bf16x8 av[2], bp[2];
        #pragma unroll
        for (int dt = 0; dt < 2; ++dt) {
            const int d = dt * 16 + lm;
            av[dt] = *(const bf16x8*)(sm + 32768 + d * 256 + (cb ^ ((d & 7) << 4)));
        }
        #pragma unroll
        for (int t = 0; t < 2; ++t) {
            const int q = (wv * 2 + t) * 16 + lm;
            bp[t] = *(const bf16x8*)(sm + q * 256 + (cb ^ ((q & 7) << 4)));
        }
        #pragma unroll
        for (int dt = 0; dt < 2; ++dt)
            #pragma unroll
            for (int t = 0; t < 2; ++t)
                o[dt][t] = __builtin_amdgcn_mfma_f32_16x16x32_bf16(av[dt], bp[t], o[dt][t], 0, 0, 0);
    }

    const int dd = ch >> 3, nn = ch & 7;
    unsigned short* zb = z + ((size_t)(b * DIM_ + dd)) * (H_ * DM_);
    #pragma unroll
    for (int dt = 0; dt < 2; ++dt)
        #pragma unroll
        for (int t = 0; t < 2; ++t) {
            const int q  = (wv * 2 + t) * 16 + lm;
            const int d0 = dt * 16 + lk * 4;
            unsigned u0 = cvtpk(o[dt][t][0], o[dt][t][1]);
            unsigned u1 = cvtpk(o[dt][t][2], o[dt][t][3]);
            *(uint2*)(zb + (size_t)q * DM_ + nn * 32 + d0) = make_uint2(u0, u1);
        }
}

// ============================================================================
// Kernel 3: W -> bf16 hi/lo split. Unchanged.
// ============================================================================
__global__ __launch_bounds__(256) void prep_w(
    const float* __restrict__ w, unsigned short* __restrict__ wh,
    unsigned short* __restrict__ wl)
{
    const int i = blockIdx.x * 1024 + threadIdx.x * 4;
    float4 v = *(const float4*)(w + i);
    float vv[4] = { v.x, v.y, v.z, v.w };
    unsigned short h[4], lo[4];
    #pragma unroll
    for (int j = 0; j < 4; ++j) {
        h[j] = f2bfu(vv[j]);
        float hf = __uint_as_float(((unsigned)h[j]) << 16);
        lo[j] = f2bfu(vv[j] - hf);
    }
    *(uint2*)(wh + i) = make_uint2((unsigned)h[0] | ((unsigned)h[1] << 16),
                                   (unsigned)h[2] | ((unsigned)h[3] << 16));
    *(uint2*)(wl + i) = make_uint2((unsigned)lo[0] | ((unsigned)lo[1] << 16),
                                   (unsigned)lo[2] | ((unsigned)lo[3] << 16));
}

// ============================================================================
// Kernel 4: MFMA out-projection, v3.
// Per (b,d) block (512 blocks, 256 thr = 4 waves). Wave owns 32 rows (2 M-frags).
// W (hi+lo) per-kc 32KB slices double-buffered in LDS via global_load_lds;
// A (z rows) in registers, prefetched one kc ahead. acc accumulates hi+lo.
// LDS slice layout: [ph][256 wrow][32 col] bf16, 64B rows -> conflict-free b128.
// ============================================================================
__global__ __launch_bounds__(256) void proj_kernel(
    const unsigned short* __restrict__ zz, const unsigned short* __restrict__ wh,
    const unsigned short* __restrict__ wl, const float* __restrict__ bias,
    float* __restrict__ out)
{
    __shared__ __align__(16) unsigned char sm[65536];   // 2 bufs x 32KB
    const int tid = threadIdx.x;
    const int l = tid & 63, wv = tid >> 6, lm = l & 15, lk = l >> 4;
    const unsigned short* zs = zz + (size_t)blockIdx.x * 32768;

    // staging: flat 16B chunk c = i*256+tid; ph=i>>2; row=(i&3)*64+(tid>>2); cc=tid&3
    const int g_off = (tid >> 2) * 256 + (tid & 3) * 8;   // elements within W
    const int lds_wv = wv * 1024;                          // wave-uniform lane base

    const int arow0 = wv * 32 + lm;

    f32x4 acc[2][16];
    #pragma unroll
    for (int t = 0; t < 2; ++t)
        #pragma unroll
        for (int nt = 0; nt < 16; ++nt) acc[t][nt] = 0;

    bf16x8 areg[2][2];

    // ---- prologue: stage kc=0 into buf0; load A[0] ----
    #pragma unroll
    for (int i = 0; i < 8; ++i) {
        const unsigned short* g = (i < 4 ? wh : wl) + g_off + (i & 3) * 16384;
        gl_lds16(g, sm + i * 4096 + lds_wv);
    }
    #pragma unroll
    for (int t = 0; t < 2; ++t)
        areg[0][t] = *(const bf16x8*)(zs + (size_t)(arow0 + t * 16) * 256 + lk * 8);

    __syncthreads();   // drains vmcnt -> buf0 staged

    #pragma unroll
    for (int kc = 0; kc < 8; ++kc) {
        const int buf = kc & 1;
        if (kc < 7) {
            // stage next slice into buf^1 (in flight during this step's compute)
            #pragma unroll
            for (int i = 0; i < 8; ++i) {
                const unsigned short* g = (i < 4 ? wh : wl) + g_off + (i & 3) * 16384 + (kc + 1) * 32;
                gl_lds16(g, sm + (buf ^ 1) * 32768 + i * 4096 + lds_wv);
            }
            // prefetch next A fragments
            #pragma unroll
            for (int t = 0; t < 2; ++t)
                areg[buf ^ 1][t] = *(const bf16x8*)(zs + (size_t)(arow0 + t * 16) * 256 + (kc + 1) * 32 + lk * 8);
        }
        // compute from buf
        #pragma unroll
        for (int ph = 0; ph < 2; ++ph)
            #pragma unroll
            for (int nt = 0; nt < 16; ++nt) {
                bf16x8 bf = *(const bf16x8*)(sm + buf * 32768 + ph * 16384 + nt * 1024 + lm * 64 + lk * 16);
                acc[0][nt] = __builtin_amdgcn_mfma_f32_16x16x32_bf16(areg[buf][0], bf, acc[0][nt], 0, 0, 0);
                acc[1][nt] = __builtin_amdgcn_mfma_f32_16x16x32_bf16(areg[buf][1], bf, acc[1][nt], 0, 0, 0);
            }
        __syncthreads();   // drains next-slice staging; protects buf^1 overwrite
    }

    // ---- epilogue ----
    float* ob = out + (size_t)blockIdx.x * 32768;
    #pragma unroll
    for (int t = 0; t < 2; ++t)
        #pragma unroll
        for (int nt = 0; nt < 16; ++nt) {
            const float bv = bias[nt * 16 + lm];
            #pragma unroll
            for (int rg = 0; rg < 4; ++rg)
                ob[(size_t)(wv * 32 + t * 16 + lk * 4 + rg) * 256 + nt * 16 + lm] = acc[t][nt][rg] + bv;
        }
}

// ============================================================================
extern "C" void kernel_launch(void* const* d_in, const int* in_sizes, int n_in,
                              void* d_out, int out_size, void* d_ws, size_t ws_size,
                              hipStream_t stream)
{
    const float* x  = (const float*)d_in[0];
    const float* w1 = (const float*)d_in[1];
    const float* w2 = (const float*)d_in[2];
    const float* wo = (const float*)d_in[3];
    const float* wb = (const float*)d_in[4];
    float* out = (float*)d_out;

    unsigned short* y2 = (unsigned short*)d_ws;                    // 100,663,296 B
    unsigned short* zz = y2 + (size_t)B_ * C3_ * H_ * WP_;         // + 33,554,432 B
    unsigned short* wh = y2;                                       // overlays dead y2 (after attn)
    unsigned short* wl = y2 + 65536;

    conv_kernel<<<dim3(8192), dim3(256), 0, stream>>>(x, w1, w2, y2);
    attn_kernel<<<dim3(4096), dim3(256), 0, stream>>>(y2, zz);
    prep_w<<<dim3(64), dim3(256), 0, stream>>>(wo, wh, wl);
    proj_kernel<<<dim3(512), dim3(256), 0, stream>>>(zz, wh, wl, wb, out);
}

// Round 4
// 122.623 us; speedup vs baseline: 4.2494x; 1.1938x over previous
//
#include <hip/hip_runtime.h>
#include <stdint.h>

#define B_   32
#define DIM_ 16
#define H_   128
#define DM_  256
#define NH_  8
#define WP_  32     // DM/NH
#define C3_  384    // 3*NH*DIM

typedef short bf16x8 __attribute__((ext_vector_type(8)));
typedef float f32x4  __attribute__((ext_vector_type(4)));

__device__ __forceinline__ unsigned short f2bfu(float v) {
    unsigned int x = __float_as_uint(v);
    x += 0x7fffu + ((x >> 16) & 1u);   // RNE
    return (unsigned short)(x >> 16);
}
__device__ __forceinline__ unsigned cvtpk(float lo, float hi) {
    unsigned r;
    asm("v_cvt_pk_bf16_f32 %0, %1, %2" : "=v"(r) : "v"(lo), "v"(hi));
    return r;
}
// async global->LDS, 16B per lane; lds dest = wave-uniform base + lane*16
__device__ __forceinline__ void gl_lds16(const void* g, void* l) {
    __builtin_amdgcn_global_load_lds(
        (const __attribute__((address_space(1))) unsigned int*)g,
        (__attribute__((address_space(3))) unsigned int*)l, 16, 0, 0);
}

// ============================================================================
// Kernel 1 (v2): fused conv1+conv2 with tap-sharing.
// Each thread owns 8 consecutive h for one (b,g,wp): computes u[r]=w2·x[row r]
// once for 12 rows (8 + 4 halo), then y[h]=Σ_t w1[t]u[h+t] — 17 MAC/output
// vs 40 before. x patch 12x8 fp32 held in registers (96 VGPR).
// Grid: 32 b * 16 g * 2 ht = 1024 blocks, 256 thr (8 hl x 32 wp).
// ============================================================================
__global__ __launch_bounds__(256) void conv_kernel(
    const float* __restrict__ x, const float* __restrict__ w1,
    const float* __restrict__ w2, unsigned short* __restrict__ y2)
{
    const int bid = blockIdx.x;
    const int ht = bid & 1;
    const int g  = (bid >> 1) & 15;
    const int b  = bid >> 5;
    const int tid = threadIdx.x;
    const int wp = tid & 31;
    const int hl = tid >> 5;          // 0..7
    const int h0 = ht * 64 + hl * 8;  // first output h of this thread

    const float* xbase = x + ((size_t)(b * DIM_ + g) * H_) * DM_ + wp * 8;

    float xr[12][8];
    #pragma unroll
    for (int r = 0; r < 12; ++r) {
        const int hr = h0 - 2 + r;
        if (hr >= 0 && hr < H_) {
            const float4* p = (const float4*)(xbase + (size_t)hr * DM_);
            float4 a = p[0], c = p[1];
            xr[r][0] = a.x; xr[r][1] = a.y; xr[r][2] = a.z; xr[r][3] = a.w;
            xr[r][4] = c.x; xr[r][5] = c.y; xr[r][6] = c.z; xr[r][7] = c.w;
        } else {
            #pragma unroll
            for (int j = 0; j < 8; ++j) xr[r][j] = 0.f;
        }
    }

    unsigned short* yb = y2 + (((size_t)(b * C3_ + g * 24)) * H_ + h0) * WP_ + wp;

    for (int oc = 0; oc < 24; ++oc) {
        const int o = g * 24 + oc;
        const float* pw1 = w1 + o * 5;
        const float* pw2 = w2 + o * 8;
        float w1r[5], w2r[8];
        #pragma unroll
        for (int t = 0; t < 5; ++t) w1r[t] = pw1[t];
        #pragma unroll
        for (int j = 0; j < 8; ++j) w2r[j] = pw2[j];

        float u[12];
        #pragma unroll
        for (int r = 0; r < 12; ++r) {
            float s = w2r[0] * xr[r][0];
            #pragma unroll
            for (int j = 1; j < 8; ++j) s = fmaf(w2r[j], xr[r][j], s);
            u[r] = s;
        }

        #pragma unroll
        for (int hh = 0; hh < 8; ++hh) {
            float yv = w1r[0] * u[hh];
            #pragma unroll
            for (int t = 1; t < 5; ++t) yv = fmaf(w1r[t], u[hh + t], yv);
            yb[(size_t)oc * (H_ * WP_) + hh * WP_] = f2bfu(yv);
        }
    }
}

// ============================================================================
// Kernel 2: MFMA attention per (b, ch). Unchanged (known-good).
// ============================================================================
__global__ __launch_bounds__(256) void attn_kernel(
    const unsigned short* __restrict__ y2, unsigned short* __restrict__ z)
{
    __shared__ __align__(16) unsigned char sm[40960];

    const int tid = threadIdx.x;
    const int ch = blockIdx.x & 127, b = blockIdx.x >> 7;
    const size_t base = ((size_t)(b * C3_ + ch)) * 4096;
    const uint4* qg = (const uint4*)(y2 + base);
    const uint4* kg = (const uint4*)(y2 + base + 128 * 4096);
    const uint4* vg = (const uint4*)(y2 + base + 256 * 4096);

    #pragma unroll
    for (int r = 0; r < 2; ++r) {
        const int ci  = tid + r * 256;
        const int row = ci >> 2;
        const int c   = ci & 3;
        const int cx  = c ^ ((row >> 1) & 3);
        *(uint4*)(sm + row * 64 + cx * 16)        = qg[ci];
        *(uint4*)(sm + 8192 + row * 64 + cx * 16) = kg[ci];
        uint4 v = vg[ci];
        unsigned short vs[8];
        vs[0] = (unsigned short)(v.x & 0xffffu); vs[1] = (unsigned short)(v.x >> 16);
        vs[2] = (unsigned short)(v.y & 0xffffu); vs[3] = (unsigned short)(v.y >> 16);
        vs[4] = (unsigned short)(v.z & 0xffffu); vs[5] = (unsigned short)(v.z >> 16);
        vs[6] = (unsigned short)(v.w & 0xffffu); vs[7] = (unsigned short)(v.w >> 16);
        const int d0 = c * 8;
        #pragma unroll
        for (int j = 0; j < 8; ++j) {
            const int d = d0 + j;
            *(unsigned short*)(sm + 32768 + d * 256 + ((row * 2) ^ ((d & 7) << 4))) = vs[j];
        }
    }
    __syncthreads();

    const int l  = tid & 63, wv = tid >> 6;
    const int lm = l & 15,  lk = l >> 4;

    bf16x8 qf[2];
    #pragma unroll
    for (int t = 0; t < 2; ++t) {
        const int q = (wv * 2 + t) * 16 + lm;
        qf[t] = *(const bf16x8*)(sm + q * 64 + ((lk ^ ((q >> 1) & 3)) << 4));
    }
    f32x4 acc[8][2];
    #pragma unroll
    for (int rt = 0; rt < 8; ++rt) {
        acc[rt][0] = 0; acc[rt][1] = 0;
    }
    #pragma unroll
    for (int rt = 0; rt < 8; ++rt) {
        const int kr = rt * 16 + lm;
        bf16x8 kf = *(const bf16x8*)(sm + 8192 + kr * 64 + ((lk ^ ((kr >> 1) & 3)) << 4));
        acc[rt][0] = __builtin_amdgcn_mfma_f32_16x16x32_bf16(kf, qf[0], acc[rt][0], 0, 0, 0);
        acc[rt][1] = __builtin_amdgcn_mfma_f32_16x16x32_bf16(kf, qf[1], acc[rt][1], 0, 0, 0);
    }

    const float Cc = 0.17677669529663687f * 1.4426950408889634f;
    float inv[2];
    #pragma unroll
    for (int t = 0; t < 2; ++t) {
        float m = acc[0][t][0];
        #pragma unroll
        for (int rt = 0; rt < 8; ++rt)
            #pragma unroll
            for (int rg = 0; rg < 4; ++rg) m = fmaxf(m, acc[rt][t][rg]);
        m = fmaxf(m, __shfl_xor(m, 16));
        m = fmaxf(m, __shfl_xor(m, 32));
        float s = 0.f;
        #pragma unroll
        for (int rt = 0; rt < 8; ++rt)
            #pragma unroll
            for (int rg = 0; rg < 4; ++rg) {
                float p = exp2f((acc[rt][t][rg] - m) * Cc);
                acc[rt][t][rg] = p; s += p;
            }
        s += __shfl_xor(s, 16);
        s += __shfl_xor(s, 32);
        inv[t] = 1.0f / s;
    }

    __syncthreads();

    #pragma unroll
    for (int t = 0; t < 2; ++t) {
        const int q = (wv * 2 + t) * 16 + lm;
        #pragma unroll
        for (int rt = 0; rt < 8; ++rt) {
            unsigned u0 = cvtpk(acc[rt][t][0] * inv[t], acc[rt][t][1] * inv[t]);
            unsigned u1 = cvtpk(acc[rt][t][2] * inv[t], acc[rt][t][3] * inv[t]);
            const int kb = rt * 32 + lk * 8;
            *(uint2*)(sm + q * 256 + (kb ^ ((q & 7) << 4))) = make_uint2(u0, u1);
        }
    }
    __syncthreads();

    f32x4 o[2][2];
    o[0][0] = 0; o[0][1] = 0; o[1][0] = 0; o[1][1] = 0;
    #pragma unroll
    for (int kc = 0; kc < 4; ++kc) {
        const int cb = kc * 64 + lk * 16;
        bf16x8 av[2], bp[2];
        #pragma unroll
        for (int dt = 0; dt < 2; ++dt) {
            const int d = dt * 16 + lm;
            av[dt] = *(const bf16x8*)(sm + 32768 + d * 256 + (cb ^ ((d & 7) << 4)));
        }
        #pragma unroll
        for (int t = 0; t < 2; ++t) {
            const int q = (wv * 2 + t) * 16 + lm;
            bp[t] = *(const bf16x8*)(sm + q * 256 + (cb ^ ((q & 7) << 4)));
        }
        #pragma unroll
        for (int dt = 0; dt < 2; ++dt)
            #pragma unroll
            for (int t = 0; t < 2; ++t)
                o[dt][t] = __builtin_amdgcn_mfma_f32_16x16x32_bf16(av[dt], bp[t], o[dt][t], 0, 0, 0);
    }

    const int dd = ch >> 3, nn = ch & 7;
    unsigned short* zb = z + ((size_t)(b * DIM_ + dd)) * (H_ * DM_);
    #pragma unroll
    for (int dt = 0; dt < 2; ++dt)
        #pragma unroll
        for (int t = 0; t < 2; ++t) {
            const int q  = (wv * 2 + t) * 16 + lm;
            const int d0 = dt * 16 + lk * 4;
            unsigned u0 = cvtpk(o[dt][t][0], o[dt][t][1]);
            unsigned u1 = cvtpk(o[dt][t][2], o[dt][t][3]);
            *(uint2*)(zb + (size_t)q * DM_ + nn * 32 + d0) = make_uint2(u0, u1);
        }
}

// ============================================================================
// Kernel 3: W -> bf16 hi/lo split. Unchanged.
// ============================================================================
__global__ __launch_bounds__(256) void prep_w(
    const float* __restrict__ w, unsigned short* __restrict__ wh,
    unsigned short* __restrict__ wl)
{
    const int i = blockIdx.x * 1024 + threadIdx.x * 4;
    float4 v = *(const float4*)(w + i);
    float vv[4] = { v.x, v.y, v.z, v.w };
    unsigned short h[4], lo[4];
    #pragma unroll
    for (int j = 0; j < 4; ++j) {
        h[j] = f2bfu(vv[j]);
        float hf = __uint_as_float(((unsigned)h[j]) << 16);
        lo[j] = f2bfu(vv[j] - hf);
    }
    *(uint2*)(wh + i) = make_uint2((unsigned)h[0] | ((unsigned)h[1] << 16),
                                   (unsigned)h[2] | ((unsigned)h[3] << 16));
    *(uint2*)(wl + i) = make_uint2((unsigned)lo[0] | ((unsigned)lo[1] << 16),
                                   (unsigned)lo[2] | ((unsigned)lo[3] << 16));
}

// ============================================================================
// Kernel 4: MFMA out-projection. Unchanged (known-good).
// ============================================================================
__global__ __launch_bounds__(256) void proj_kernel(
    const unsigned short* __restrict__ zz, const unsigned short* __restrict__ wh,
    const unsigned short* __restrict__ wl, const float* __restrict__ bias,
    float* __restrict__ out)
{
    __shared__ __align__(16) unsigned char sm[65536];   // 2 bufs x 32KB
    const int tid = threadIdx.x;
    const int l = tid & 63, wv = tid >> 6, lm = l & 15, lk = l >> 4;
    const unsigned short* zs = zz + (size_t)blockIdx.x * 32768;

    const int g_off = (tid >> 2) * 256 + (tid & 3) * 8;   // elements within W
    const int lds_wv = wv * 1024;                          // wave-uniform lane base

    const int arow0 = wv * 32 + lm;

    f32x4 acc[2][16];
    #pragma unroll
    for (int t = 0; t < 2; ++t)
        #pragma unroll
        for (int nt = 0; nt < 16; ++nt) acc[t][nt] = 0;

    bf16x8 areg[2][2];

    #pragma unroll
    for (int i = 0; i < 8; ++i) {
        const unsigned short* g = (i < 4 ? wh : wl) + g_off + (i & 3) * 16384;
        gl_lds16(g, sm + i * 4096 + lds_wv);
    }
    #pragma unroll
    for (int t = 0; t < 2; ++t)
        areg[0][t] = *(const bf16x8*)(zs + (size_t)(arow0 + t * 16) * 256 + lk * 8);

    __syncthreads();

    #pragma unroll
    for (int kc = 0; kc < 8; ++kc) {
        const int buf = kc & 1;
        if (kc < 7) {
            #pragma unroll
            for (int i = 0; i < 8; ++i) {
                const unsigned short* g = (i < 4 ? wh : wl) + g_off + (i & 3) * 16384 + (kc + 1) * 32;
                gl_lds16(g, sm + (buf ^ 1) * 32768 + i * 4096 + lds_wv);
            }
            #pragma unroll
            for (int t = 0; t < 2; ++t)
                areg[buf ^ 1][t] = *(const bf16x8*)(zs + (size_t)(arow0 + t * 16) * 256 + (kc + 1) * 32 + lk * 8);
        }
        #pragma unroll
        for (int ph = 0; ph < 2; ++ph)
            #pragma unroll
            for (int nt = 0; nt < 16; ++nt) {
                bf16x8 bf = *(const bf16x8*)(sm + buf * 32768 + ph * 16384 + nt * 1024 + lm * 64 + lk * 16);
                acc[0][nt] = __builtin_amdgcn_mfma_f32_16x16x32_bf16(areg[buf][0], bf, acc[0][nt], 0, 0, 0);
                acc[1][nt] = __builtin_amdgcn_mfma_f32_16x16x32_bf16(areg[buf][1], bf, acc[1][nt], 0, 0, 0);
            }
        __syncthreads();
    }

    float* ob = out + (size_t)blockIdx.x * 32768;
    #pragma unroll
    for (int t = 0; t < 2; ++t)
        #pragma unroll
        for (int nt = 0; nt < 16; ++nt) {
            const float bv = bias[nt * 16 + lm];
            #pragma unroll
            for (int rg = 0; rg < 4; ++rg)
                ob[(size_t)(wv * 32 + t * 16 + lk * 4 + rg) * 256 + nt * 16 + lm] = acc[t][nt][rg] + bv;
        }
}

// ============================================================================
extern "C" void kernel_launch(void* const* d_in, const int* in_sizes, int n_in,
                              void* d_out, int out_size, void* d_ws, size_t ws_size,
                              hipStream_t stream)
{
    const float* x  = (const float*)d_in[0];
    const float* w1 = (const float*)d_in[1];
    const float* w2 = (const float*)d_in[2];
    const float* wo = (const float*)d_in[3];
    const float* wb = (const float*)d_in[4];
    float* out = (float*)d_out;

    unsigned short* y2 = (unsigned short*)d_ws;                    // 100,663,296 B
    unsigned short* zz = y2 + (size_t)B_ * C3_ * H_ * WP_;         // + 33,554,432 B
    unsigned short* wh = y2;                                       // overlays dead y2 (after attn)
    unsigned short* wl = y2 + 65536;

    conv_kernel<<<dim3(1024), dim3(256), 0, stream>>>(x, w1, w2, y2);
    attn_kernel<<<dim3(4096), dim3(256), 0, stream>>>(y2, zz);
    prep_w<<<dim3(64), dim3(256), 0, stream>>>(wo, wh, wl);
    proj_kernel<<<dim3(512), dim3(256), 0, stream>>>(zz, wh, wl, wb, out);
}

// Round 6
// 118.852 us; speedup vs baseline: 4.3842x; 1.0317x over previous
//
#include <hip/hip_runtime.h>
#include <stdint.h>

#define B_   32
#define DIM_ 16
#define H_   128
#define DM_  256
#define NH_  8
#define WP_  32     // DM/NH
#define C3_  384    // 3*NH*DIM

typedef short bf16x8 __attribute__((ext_vector_type(8)));
typedef float f32x4  __attribute__((ext_vector_type(4)));

__device__ __forceinline__ unsigned short f2bfu(float v) {
    unsigned int x = __float_as_uint(v);
    x += 0x7fffu + ((x >> 16) & 1u);   // RNE
    return (unsigned short)(x >> 16);
}
__device__ __forceinline__ unsigned cvtpk(float lo, float hi) {
    unsigned r;
    asm("v_cvt_pk_bf16_f32 %0, %1, %2" : "=v"(r) : "v"(lo), "v"(hi));
    return r;
}
// async global->LDS, 16B per lane; lds dest = wave-uniform base + lane*16
__device__ __forceinline__ void gl_lds16(const void* g, void* l) {
    __builtin_amdgcn_global_load_lds(
        (const __attribute__((address_space(1))) unsigned int*)g,
        (__attribute__((address_space(3))) unsigned int*)l, 16, 0, 0);
}

// ============================================================================
// Kernel 1 (v3b): fused conv1+conv2, tap-sharing + LDS-staged weights.
// v3 BUG: staged with `if(tid<384)` but blockDim=256 -> oc 16..23 garbage.
// v3b: strided staging loop (each thread stages up to 2 entries).
// Grid: 32 b * 16 g * 2 ht = 1024 blocks, 256 thr (8 hl x 32 wp).
// ============================================================================
__global__ __launch_bounds__(256) void conv_kernel(
    const float* __restrict__ x, const float* __restrict__ w1,
    const float* __restrict__ w2, unsigned short* __restrict__ y2)
{
    __shared__ float wlds[24 * 16];   // [oc][0..4]=w1, [5..12]=w2, rest pad

    const int bid = blockIdx.x;
    const int ht = bid & 1;
    const int g  = (bid >> 1) & 15;
    const int b  = bid >> 5;
    const int tid = threadIdx.x;
    const int wp = tid & 31;
    const int hl = tid >> 5;          // 0..7
    const int h0 = ht * 64 + hl * 8;  // first output h of this thread

    // ---- one-time weight staging (block-uniform); 384 entries, 256 threads ----
    for (int i = tid; i < 384; i += 256) {
        const int oc = i >> 4, ix = i & 15;
        const int o = g * 24 + oc;
        float v = 0.f;
        if (ix < 5)       v = w1[o * 5 + ix];
        else if (ix < 13) v = w2[o * 8 + (ix - 5)];
        wlds[i] = v;
    }

    const float* xbase = x + ((size_t)(b * DIM_ + g) * H_) * DM_ + wp * 8;

    float xr[12][8];
    #pragma unroll
    for (int r = 0; r < 12; ++r) {
        const int hr = h0 - 2 + r;
        if (hr >= 0 && hr < H_) {
            const float4* p = (const float4*)(xbase + (size_t)hr * DM_);
            float4 a = p[0], c = p[1];
            xr[r][0] = a.x; xr[r][1] = a.y; xr[r][2] = a.z; xr[r][3] = a.w;
            xr[r][4] = c.x; xr[r][5] = c.y; xr[r][6] = c.z; xr[r][7] = c.w;
        } else {
            #pragma unroll
            for (int j = 0; j < 8; ++j) xr[r][j] = 0.f;
        }
    }
    __syncthreads();

    unsigned short* yb = y2 + (((size_t)(b * C3_ + g * 24)) * H_ + h0) * WP_ + wp;

    for (int oc = 0; oc < 24; ++oc) {
        const float* wo_ = &wlds[oc * 16];
        float w1r[5], w2r[8];
        {
            float4 a = *(const float4*)(wo_);       // w1[0..3]
            float4 c = *(const float4*)(wo_ + 4);   // w1[4], w2[0..2]
            float4 d = *(const float4*)(wo_ + 8);   // w2[3..6]
            w1r[0] = a.x; w1r[1] = a.y; w1r[2] = a.z; w1r[3] = a.w;
            w1r[4] = c.x;
            w2r[0] = c.y; w2r[1] = c.z; w2r[2] = c.w;
            w2r[3] = d.x; w2r[4] = d.y; w2r[5] = d.z; w2r[6] = d.w;
            w2r[7] = wo_[12];
        }

        float u[12];
        #pragma unroll
        for (int r = 0; r < 12; ++r) {
            float s = w2r[0] * xr[r][0];
            #pragma unroll
            for (int j = 1; j < 8; ++j) s = fmaf(w2r[j], xr[r][j], s);
            u[r] = s;
        }

        #pragma unroll
        for (int hh = 0; hh < 8; ++hh) {
            float yv = w1r[0] * u[hh];
            #pragma unroll
            for (int t = 1; t < 5; ++t) yv = fmaf(w1r[t], u[hh + t], yv);
            yb[(size_t)oc * (H_ * WP_) + hh * WP_] = f2bfu(yv);
        }
    }
}

// ============================================================================
// Kernel 2: MFMA attention per (b, ch). Unchanged (known-good).
// ============================================================================
__global__ __launch_bounds__(256) void attn_kernel(
    const unsigned short* __restrict__ y2, unsigned short* __restrict__ z)
{
    __shared__ __align__(16) unsigned char sm[40960];

    const int tid = threadIdx.x;
    const int ch = blockIdx.x & 127, b = blockIdx.x >> 7;
    const size_t base = ((size_t)(b * C3_ + ch)) * 4096;
    const uint4* qg = (const uint4*)(y2 + base);
    const uint4* kg = (const uint4*)(y2 + base + 128 * 4096);
    const uint4* vg = (const uint4*)(y2 + base + 256 * 4096);

    #pragma unroll
    for (int r = 0; r < 2; ++r) {
        const int ci  = tid + r * 256;
        const int row = ci >> 2;
        const int c   = ci & 3;
        const int cx  = c ^ ((row >> 1) & 3);
        *(uint4*)(sm + row * 64 + cx * 16)        = qg[ci];
        *(uint4*)(sm + 8192 + row * 64 + cx * 16) = kg[ci];
        uint4 v = vg[ci];
        unsigned short vs[8];
        vs[0] = (unsigned short)(v.x & 0xffffu); vs[1] = (unsigned short)(v.x >> 16);
        vs[2] = (unsigned short)(v.y & 0xffffu); vs[3] = (unsigned short)(v.y >> 16);
        vs[4] = (unsigned short)(v.z & 0xffffu); vs[5] = (unsigned short)(v.z >> 16);
        vs[6] = (unsigned short)(v.w & 0xffffu); vs[7] = (unsigned short)(v.w >> 16);
        const int d0 = c * 8;
        #pragma unroll
        for (int j = 0; j < 8; ++j) {
            const int d = d0 + j;
            *(unsigned short*)(sm + 32768 + d * 256 + ((row * 2) ^ ((d & 7) << 4))) = vs[j];
        }
    }
    __syncthreads();

    const int l  = tid & 63, wv = tid >> 6;
    const int lm = l & 15,  lk = l >> 4;

    bf16x8 qf[2];
    #pragma unroll
    for (int t = 0; t < 2; ++t) {
        const int q = (wv * 2 + t) * 16 + lm;
        qf[t] = *(const bf16x8*)(sm + q * 64 + ((lk ^ ((q >> 1) & 3)) << 4));
    }
    f32x4 acc[8][2];
    #pragma unroll
    for (int rt = 0; rt < 8; ++rt) {
        acc[rt][0] = 0; acc[rt][1] = 0;
    }
    #pragma unroll
    for (int rt = 0; rt < 8; ++rt) {
        const int kr = rt * 16 + lm;
        bf16x8 kf = *(const bf16x8*)(sm + 8192 + kr * 64 + ((lk ^ ((kr >> 1) & 3)) << 4));
        acc[rt][0] = __builtin_amdgcn_mfma_f32_16x16x32_bf16(kf, qf[0], acc[rt][0], 0, 0, 0);
        acc[rt][1] = __builtin_amdgcn_mfma_f32_16x16x32_bf16(kf, qf[1], acc[rt][1], 0, 0, 0);
    }

    const float Cc = 0.17677669529663687f * 1.4426950408889634f;
    float inv[2];
    #pragma unroll
    for (int t = 0; t < 2; ++t) {
        float m = acc[0][t][0];
        #pragma unroll
        for (int rt = 0; rt < 8; ++rt)
            #pragma unroll
            for (int rg = 0; rg < 4; ++rg) m = fmaxf(m, acc[rt][t][rg]);
        m = fmaxf(m, __shfl_xor(m, 16));
        m = fmaxf(m, __shfl_xor(m, 32));
        float s = 0.f;
        #pragma unroll
        for (int rt = 0; rt < 8; ++rt)
            #pragma unroll
            for (int rg = 0; rg < 4; ++rg) {
                float p = exp2f((acc[rt][t][rg] - m) * Cc);
                acc[rt][t][rg] = p; s += p;
            }
        s += __shfl_xor(s, 16);
        s += __shfl_xor(s, 32);
        inv[t] = 1.0f / s;
    }

    __syncthreads();

    #pragma unroll
    for (int t = 0; t < 2; ++t) {
        const int q = (wv * 2 + t) * 16 + lm;
        #pragma unroll
        for (int rt = 0; rt < 8; ++rt) {
            unsigned u0 = cvtpk(acc[rt][t][0] * inv[t], acc[rt][t][1] * inv[t]);
            unsigned u1 = cvtpk(acc[rt][t][2] * inv[t], acc[rt][t][3] * inv[t]);
            const int kb = rt * 32 + lk * 8;
            *(uint2*)(sm + q * 256 + (kb ^ ((q & 7) << 4))) = make_uint2(u0, u1);
        }
    }
    __syncthreads();

    f32x4 o[2][2];
    o[0][0] = 0; o[0][1] = 0; o[1][0] = 0; o[1][1] = 0;
    #pragma unroll
    for (int kc = 0; kc < 4; ++kc) {
        const int cb = kc * 64 + lk * 16;
        bf16x8 av[2], bp[2];
        #pragma unroll
        for (int dt = 0; dt < 2; ++dt) {
            const int d = dt * 16 + lm;
            av[dt] = *(const bf16x8*)(sm + 32768 + d * 256 + (cb ^ ((d & 7) << 4)));
        }
        #pragma unroll
        for (int t = 0; t < 2; ++t) {
            const int q = (wv * 2 + t) * 16 + lm;
            bp[t] = *(const bf16x8*)(sm + q * 256 + (cb ^ ((q & 7) << 4)));
        }
        #pragma unroll
        for (int dt = 0; dt < 2; ++dt)
            #pragma unroll
            for (int t = 0; t < 2; ++t)
                o[dt][t] = __builtin_amdgcn_mfma_f32_16x16x32_bf16(av[dt], bp[t], o[dt][t], 0, 0, 0);
    }

    const int dd = ch >> 3, nn = ch & 7;
    unsigned short* zb = z + ((size_t)(b * DIM_ + dd)) * (H_ * DM_);
    #pragma unroll
    for (int dt = 0; dt < 2; ++dt)
        #pragma unroll
        for (int t = 0; t < 2; ++t) {
            const int q  = (wv * 2 + t) * 16 + lm;
            const int d0 = dt * 16 + lk * 4;
            unsigned u0 = cvtpk(o[dt][t][0], o[dt][t][1]);
            unsigned u1 = cvtpk(o[dt][t][2], o[dt][t][3]);
            *(uint2*)(zb + (size_t)q * DM_ + nn * 32 + d0) = make_uint2(u0, u1);
        }
}

// ============================================================================
// Kernel 3: W -> bf16 hi/lo split. Unchanged.
// ============================================================================
__global__ __launch_bounds__(256) void prep_w(
    const float* __restrict__ w, unsigned short* __restrict__ wh,
    unsigned short* __restrict__ wl)
{
    const int i = blockIdx.x * 1024 + threadIdx.x * 4;
    float4 v = *(const float4*)(w + i);
    float vv[4] = { v.x, v.y, v.z, v.w };
    unsigned short h[4], lo[4];
    #pragma unroll
    for (int j = 0; j < 4; ++j) {
        h[j] = f2bfu(vv[j]);
        float hf = __uint_as_float(((unsigned)h[j]) << 16);
        lo[j] = f2bfu(vv[j] - hf);
    }
    *(uint2*)(wh + i) = make_uint2((unsigned)h[0] | ((unsigned)h[1] << 16),
                                   (unsigned)h[2] | ((unsigned)h[3] << 16));
    *(uint2*)(wl + i) = make_uint2((unsigned)lo[0] | ((unsigned)lo[1] << 16),
                                   (unsigned)lo[2] | ((unsigned)lo[3] << 16));
}

// ============================================================================
// Kernel 4: MFMA out-projection. Unchanged (known-good).
// ============================================================================
__global__ __launch_bounds__(256) void proj_kernel(
    const unsigned short* __restrict__ zz, const unsigned short* __restrict__ wh,
    const unsigned short* __restrict__ wl, const float* __restrict__ bias,
    float* __restrict__ out)
{
    __shared__ __align__(16) unsigned char sm[65536];   // 2 bufs x 32KB
    const int tid = threadIdx.x;
    const int l = tid & 63, wv = tid >> 6, lm = l & 15, lk = l >> 4;
    const unsigned short* zs = zz + (size_t)blockIdx.x * 32768;

    const int g_off = (tid >> 2) * 256 + (tid & 3) * 8;   // elements within W
    const int lds_wv = wv * 1024;                          // wave-uniform lane base

    const int arow0 = wv * 32 + lm;

    f32x4 acc[2][16];
    #pragma unroll
    for (int t = 0; t < 2; ++t)
        #pragma unroll
        for (int nt = 0; nt < 16; ++nt) acc[t][nt] = 0;

    bf16x8 areg[2][2];

    #pragma unroll
    for (int i = 0; i < 8; ++i) {
        const unsigned short* g = (i < 4 ? wh : wl) + g_off + (i & 3) * 16384;
        gl_lds16(g, sm + i * 4096 + lds_wv);
    }
    #pragma unroll
    for (int t = 0; t < 2; ++t)
        areg[0][t] = *(const bf16x8*)(zs + (size_t)(arow0 + t * 16) * 256 + lk * 8);

    __syncthreads();

    #pragma unroll
    for (int kc = 0; kc < 8; ++kc) {
        const int buf = kc & 1;
        if (kc < 7) {
            #pragma unroll
            for (int i = 0; i < 8; ++i) {
                const unsigned short* g = (i < 4 ? wh : wl) + g_off + (i & 3) * 16384 + (kc + 1) * 32;
                gl_lds16(g, sm + (buf ^ 1) * 32768 + i * 4096 + lds_wv);
            }
            #pragma unroll
            for (int t = 0; t < 2; ++t)
                areg[buf ^ 1][t] = *(const bf16x8*)(zs + (size_t)(arow0 + t * 16) * 256 + (kc + 1) * 32 + lk * 8);
        }
        #pragma unroll
        for (int ph = 0; ph < 2; ++ph)
            #pragma unroll
            for (int nt = 0; nt < 16; ++nt) {
                bf16x8 bf = *(const bf16x8*)(sm + buf * 32768 + ph * 16384 + nt * 1024 + lm * 64 + lk * 16);
                acc[0][nt] = __builtin_amdgcn_mfma_f32_16x16x32_bf16(areg[buf][0], bf, acc[0][nt], 0, 0, 0);
                acc[1][nt] = __builtin_amdgcn_mfma_f32_16x16x32_bf16(areg[buf][1], bf, acc[1][nt], 0, 0, 0);
            }
        __syncthreads();
    }

    float* ob = out + (size_t)blockIdx.x * 32768;
    #pragma unroll
    for (int t = 0; t < 2; ++t)
        #pragma unroll
        for (int nt = 0; nt < 16; ++nt) {
            const float bv = bias[nt * 16 + lm];
            #pragma unroll
            for (int rg = 0; rg < 4; ++rg)
                ob[(size_t)(wv * 32 + t * 16 + lk * 4 + rg) * 256 + nt * 16 + lm] = acc[t][nt][rg] + bv;
        }
}

// ============================================================================
extern "C" void kernel_launch(void* const* d_in, const int* in_sizes, int n_in,
                              void* d_out, int out_size, void* d_ws, size_t ws_size,
                              hipStream_t stream)
{
    const float* x  = (const float*)d_in[0];
    const float* w1 = (const float*)d_in[1];
    const float* w2 = (const float*)d_in[2];
    const float* wo = (const float*)d_in[3];
    const float* wb = (const float*)d_in[4];
    float* out = (float*)d_out;

    unsigned short* y2 = (unsigned short*)d_ws;                    // 100,663,296 B
    unsigned short* zz = y2 + (size_t)B_ * C3_ * H_ * WP_;         // + 33,554,432 B
    unsigned short* wh = y2;                                       // overlays dead y2 (after attn)
    unsigned short* wl = y2 + 65536;

    conv_kernel<<<dim3(1024), dim3(256), 0, stream>>>(x, w1, w2, y2);
    attn_kernel<<<dim3(4096), dim3(256), 0, stream>>>(y2, zz);
    prep_w<<<dim3(64), dim3(256), 0, stream>>>(wo, wh, wl);
    proj_kernel<<<dim3(512), dim3(256), 0, stream>>>(zz, wh, wl, wb, out);
}